// Round 1
// baseline (1564.840 us; speedup 1.0000x reference)
//
#include <hip/hip_runtime.h>
#include <stdint.h>

// EfficientFusionLayer on MI355X (gfx950).
// B=16384, DIM=1024, HID=2048, fp32 in/out; internals bf16 MFMA (16x16x32).
// seq-len-1 MHA: softmax over one key == 1 -> attn(x) = (x@Wv^T+bv)@Wo^T+bo.

typedef unsigned short u16;
typedef __bf16 bf16x8 __attribute__((ext_vector_type(8)));
typedef float f32x4 __attribute__((ext_vector_type(4)));

__device__ __forceinline__ u16 f2bf(float f) {
    uint32_t x = __float_as_uint(f);
    uint32_t r = (x + 0x7fffu + ((x >> 16) & 1u)) >> 16;   // round-nearest-even
    return (u16)r;
}
__device__ __forceinline__ float bf2f(u16 u) {
    return __uint_as_float(((uint32_t)u) << 16);
}

// ---------------------------------------------------------------------------
// fp32 -> bf16 convert (4 elems/thread, n % 1024 == 0)
__global__ __launch_bounds__(256) void cvtk(const float* __restrict__ src,
                                            u16* __restrict__ dst) {
    size_t i = ((size_t)blockIdx.x * 256 + threadIdx.x) * 4;
    float4 v = *(const float4*)&src[i];
    ushort4 o;
    o.x = f2bf(v.x); o.y = f2bf(v.y); o.z = f2bf(v.z); o.w = f2bf(v.w);
    *(ushort4*)&dst[i] = o;
}

// new_context = 0.5*(v_out + t_out)
__global__ __launch_bounds__(256) void ctxk(const float* __restrict__ a,
                                            const float* __restrict__ b,
                                            float* __restrict__ o) {
    size_t i = ((size_t)blockIdx.x * 256 + threadIdx.x) * 4;
    float4 va = *(const float4*)&a[i];
    float4 vb = *(const float4*)&b[i];
    float4 vo;
    vo.x = 0.5f * (va.x + vb.x); vo.y = 0.5f * (va.y + vb.y);
    vo.z = 0.5f * (va.z + vb.z); vo.w = 0.5f * (va.w + vb.w);
    *(float4*)&o[i] = vo;
}

// ---------------------------------------------------------------------------
// LayerNorm over D=1024: out_bf16 = LN(x_f32 + s*(a1_bf16 [+ a2_bf16])) * g + be
// one block (256 thr) per row, 4 elems/thread, fp32 stats.
__global__ __launch_bounds__(256) void ln_kernel(
    const float* __restrict__ x, const u16* __restrict__ a1,
    const u16* __restrict__ a2, float s,
    const float* __restrict__ g, const float* __restrict__ be,
    u16* __restrict__ out) {
    const int tid = threadIdx.x;
    const size_t base = (size_t)blockIdx.x * 1024;
    const int i0 = tid * 4;

    float4 xv = *(const float4*)&x[base + i0];
    ushort4 u1 = *(const ushort4*)&a1[base + i0];
    float add[4] = {bf2f(u1.x), bf2f(u1.y), bf2f(u1.z), bf2f(u1.w)};
    if (a2) {
        ushort4 u2 = *(const ushort4*)&a2[base + i0];
        add[0] += bf2f(u2.x); add[1] += bf2f(u2.y);
        add[2] += bf2f(u2.z); add[3] += bf2f(u2.w);
    }
    float v[4] = {xv.x, xv.y, xv.z, xv.w};
    float sum = 0.f, ss = 0.f;
#pragma unroll
    for (int j = 0; j < 4; ++j) {
        v[j] += s * add[j];
        sum += v[j];
        ss += v[j] * v[j];
    }
#pragma unroll
    for (int o = 1; o < 64; o <<= 1) {   // wave64 butterfly
        sum += __shfl_xor(sum, o);
        ss  += __shfl_xor(ss, o);
    }
    __shared__ float s1[4], s2[4];
    if ((tid & 63) == 0) { s1[tid >> 6] = sum; s2[tid >> 6] = ss; }
    __syncthreads();
    sum = s1[0] + s1[1] + s1[2] + s1[3];
    ss  = s2[0] + s2[1] + s2[2] + s2[3];
    const float mean = sum * (1.f / 1024.f);
    const float var  = ss * (1.f / 1024.f) - mean * mean;
    const float inv  = rsqrtf(var + 1e-5f);

    float4 gv = *(const float4*)&g[i0];
    float4 bv = *(const float4*)&be[i0];
    ushort4 o4;
    o4.x = f2bf((v[0] - mean) * inv * gv.x + bv.x);
    o4.y = f2bf((v[1] - mean) * inv * gv.y + bv.y);
    o4.z = f2bf((v[2] - mean) * inv * gv.z + bv.z);
    o4.w = f2bf((v[3] - mean) * inv * gv.w + bv.w);
    *(ushort4*)&out[base + i0] = o4;
}

// ---------------------------------------------------------------------------
// NT GEMM: C[M,N] = A[M,K] @ W[N,K]^T + bias, bf16 inputs, fp32 accumulate.
// 128x128 tile, BK=32, 256 threads (4 waves, 2x2), 4x4 of 16x16x32 MFMA/wave.
// LDS k-groups XOR-swizzled (group ^= (row>>1)&3) -> 2-way (free) bank access
// on both the b128 staging writes and the b128 fragment reads.
// mode 0: bf16 out = acc+bias
// mode 1: bf16 out = relu(acc+bias)
// mode 2: fp32 out = acc+bias + bf2f(resid)
__global__ __launch_bounds__(256) void gemm_bt(
    const u16* __restrict__ A, const u16* __restrict__ W,
    const float* __restrict__ bias,
    int M, int N, int K, int mode,
    const u16* __restrict__ resid,
    u16* __restrict__ out_bf, float* __restrict__ out_f) {
    __shared__ u16 As[128 * 32];
    __shared__ u16 Bs[128 * 32];

    const int tid  = threadIdx.x;
    const int lane = tid & 63;
    const int wv   = tid >> 6;
    const int wm   = wv >> 1, wn = wv & 1;
    const int M0 = blockIdx.y * 128, N0 = blockIdx.x * 128;

    const f32x4 fz = {0.f, 0.f, 0.f, 0.f};
    f32x4 acc[4][4];
#pragma unroll
    for (int i = 0; i < 4; ++i)
#pragma unroll
        for (int j = 0; j < 4; ++j) acc[i][j] = fz;

    // staging: thread t covers 16B group (t&3) of row t>>2 (two iters of 64 rows)
    const int srow = tid >> 2;
    const int sgrp = tid & 3;
    // fragment read indices
    const int lr  = lane & 15;       // m (A) / n (B) within 16
    const int q   = lane >> 4;       // k-group quad
    const int gsw = ((q ^ ((lr >> 1) & 3)) << 3);  // swizzled k elem offset

    const u16* Ab = A + (size_t)M0 * K;
    const u16* Wb = W + (size_t)N0 * K;

    for (int k0 = 0; k0 < K; k0 += 32) {
        __syncthreads();
#pragma unroll
        for (int it = 0; it < 2; ++it) {
            const int row = srow + it * 64;
            const int kk  = ((sgrp ^ ((row >> 1) & 3)) << 3);
            *(uint4*)&As[row * 32 + kk] =
                *(const uint4*)&Ab[(size_t)row * K + k0 + sgrp * 8];
            *(uint4*)&Bs[row * 32 + kk] =
                *(const uint4*)&Wb[(size_t)row * K + k0 + sgrp * 8];
        }
        __syncthreads();

        bf16x8 af[4], bfr[4];
#pragma unroll
        for (int mi = 0; mi < 4; ++mi)
            af[mi] = *(const bf16x8*)&As[(wm * 64 + mi * 16 + lr) * 32 + gsw];
#pragma unroll
        for (int ni = 0; ni < 4; ++ni)
            bfr[ni] = *(const bf16x8*)&Bs[(wn * 64 + ni * 16 + lr) * 32 + gsw];
#pragma unroll
        for (int mi = 0; mi < 4; ++mi)
#pragma unroll
            for (int ni = 0; ni < 4; ++ni)
                acc[mi][ni] = __builtin_amdgcn_mfma_f32_16x16x32_bf16(
                    af[mi], bfr[ni], acc[mi][ni], 0, 0, 0);
    }

    // epilogue: C/D layout col = lane&15, row = (lane>>4)*4 + reg  [m89/m91]
    const int rbase = M0 + wm * 64 + (q << 2);
    const int cbase = N0 + wn * 64 + lr;
#pragma unroll
    for (int mi = 0; mi < 4; ++mi) {
#pragma unroll
        for (int ni = 0; ni < 4; ++ni) {
            const int c = cbase + ni * 16;
            const float bv = bias[c];
#pragma unroll
            for (int r = 0; r < 4; ++r) {
                const int rr = rbase + mi * 16 + r;
                float val = acc[mi][ni][r] + bv;
                if (mode == 0) {
                    out_bf[(size_t)rr * N + c] = f2bf(val);
                } else if (mode == 1) {
                    out_bf[(size_t)rr * N + c] = f2bf(val > 0.f ? val : 0.f);
                } else {
                    out_f[(size_t)rr * N + c] =
                        val + bf2f(resid[(size_t)rr * N + c]);
                }
            }
        }
    }
}

// ---------------------------------------------------------------------------
extern "C" void kernel_launch(void* const* d_in, const int* in_sizes, int n_in,
                              void* d_out, int out_size, void* d_ws, size_t ws_size,
                              hipStream_t stream) {
    const float* visual = (const float*)d_in[0];
    const float* text   = (const float*)d_in[1];
    const float* Wv_sv  = (const float*)d_in[2];
    const float* bv_sv  = (const float*)d_in[3];
    const float* Wo_sv  = (const float*)d_in[4];
    const float* bo_sv  = (const float*)d_in[5];
    const float* Wv_st  = (const float*)d_in[6];
    const float* bv_st  = (const float*)d_in[7];
    const float* Wo_st  = (const float*)d_in[8];
    const float* bo_st  = (const float*)d_in[9];
    const float* Wv_v2t = (const float*)d_in[10];
    const float* bv_v2t = (const float*)d_in[11];
    const float* Wo_v2t = (const float*)d_in[12];
    const float* bo_v2t = (const float*)d_in[13];
    const float* Wv_t2v = (const float*)d_in[14];
    const float* bv_t2v = (const float*)d_in[15];
    const float* Wo_t2v = (const float*)d_in[16];
    const float* bo_t2v = (const float*)d_in[17];
    const float* g_v1 = (const float*)d_in[18];
    const float* be_v1 = (const float*)d_in[19];
    const float* g_t1 = (const float*)d_in[20];
    const float* be_t1 = (const float*)d_in[21];
    const float* g_v2 = (const float*)d_in[22];
    const float* be_v2 = (const float*)d_in[23];
    const float* g_t2 = (const float*)d_in[24];
    const float* be_t2 = (const float*)d_in[25];
    const float* W1_v = (const float*)d_in[26];
    const float* b1_v = (const float*)d_in[27];
    const float* W2_v = (const float*)d_in[28];
    const float* b2_v = (const float*)d_in[29];
    const float* W1_t = (const float*)d_in[30];
    const float* b1_t = (const float*)d_in[31];
    const float* W2_t = (const float*)d_in[32];
    const float* b2_t = (const float*)d_in[33];

    const int Bsz = 16384, D = 1024, HID = 2048;
    const size_t SQ = (size_t)D * D;          // 1048576
    const size_t BD = (size_t)Bsz * D;        // 16777216

    // ws layout (bf16 u16*): 16 MB-elem weight region + 4 activation units.
    // total = 80 * 1048576 elems * 2B = 167,772,160 B
    u16* wb = (u16*)d_ws;
    u16* wWv_sv  = wb + 0 * SQ;
    u16* wWo_sv  = wb + 1 * SQ;
    u16* wWv_st  = wb + 2 * SQ;
    u16* wWo_st  = wb + 3 * SQ;
    u16* wWv_v2t = wb + 4 * SQ;
    u16* wWo_v2t = wb + 5 * SQ;
    u16* wWv_t2v = wb + 6 * SQ;
    u16* wWo_t2v = wb + 7 * SQ;
    u16* wW1_v = wb + 8 * SQ;    // 2M elems each from here
    u16* wW2_v = wb + 10 * SQ;
    u16* wW1_t = wb + 12 * SQ;
    u16* wW2_t = wb + 14 * SQ;
    u16* P0 = wb + 16 * SQ;
    u16* P1 = wb + 32 * SQ;
    u16* P2 = wb + 48 * SQ;
    u16* P3 = wb + 64 * SQ;
    u16* Hbuf = P1;              // 16384x2048 spans P1+P2 (dead there)

    float* out0 = (float*)d_out;
    float* out1 = out0 + BD;
    float* out2 = out0 + 2 * BD;

    auto cvt = [&](const float* src, u16* dst, size_t n) {
        cvtk<<<dim3((unsigned)(n / 1024)), dim3(256), 0, stream>>>(src, dst);
    };
    auto gemm = [&](const u16* A, const u16* W, const float* bias, int M, int N,
                    int K, int mode, const u16* resid, void* out) {
        dim3 grid((unsigned)(N / 128), (unsigned)(M / 128));
        gemm_bt<<<grid, dim3(256), 0, stream>>>(A, W, bias, M, N, K, mode,
                                                resid, (u16*)out, (float*)out);
    };
    auto ln = [&](const float* x, const u16* a1, const u16* a2, float s,
                  const float* g, const float* be, u16* out) {
        ln_kernel<<<dim3(Bsz), dim3(256), 0, stream>>>(x, a1, a2, s, g, be, out);
    };

    // weights + inputs -> bf16 (ws is re-poisoned every call; must redo)
    cvt(Wv_sv, wWv_sv, SQ);   cvt(Wo_sv, wWo_sv, SQ);
    cvt(Wv_st, wWv_st, SQ);   cvt(Wo_st, wWo_st, SQ);
    cvt(Wv_v2t, wWv_v2t, SQ); cvt(Wo_v2t, wWo_v2t, SQ);
    cvt(Wv_t2v, wWv_t2v, SQ); cvt(Wo_t2v, wWo_t2v, SQ);
    cvt(W1_v, wW1_v, 2 * SQ); cvt(W2_v, wW2_v, 2 * SQ);
    cvt(W1_t, wW1_t, 2 * SQ); cvt(W2_t, wW2_t, 2 * SQ);

    // v_self = LN(visual + attn_sv(visual))
    cvt(visual, P0, BD);
    gemm(P0, wWv_sv, bv_sv, Bsz, D, D, 0, nullptr, P1);
    gemm(P1, wWo_sv, bo_sv, Bsz, D, D, 0, nullptr, P0);
    ln(visual, P0, nullptr, 1.f, g_v1, be_v1, P1);          // P1 = VS

    // t_self = LN(text + attn_st(text))
    cvt(text, P0, BD);
    gemm(P0, wWv_st, bv_st, Bsz, D, D, 0, nullptr, P2);
    gemm(P2, wWo_st, bo_st, Bsz, D, D, 0, nullptr, P0);
    ln(text, P0, nullptr, 1.f, g_t1, be_t1, P2);            // P2 = TS

    // v_cross = attn_v2t(t_self); v_fused = LN(visual + 0.5*(VS+VC))
    gemm(P2, wWv_v2t, bv_v2t, Bsz, D, D, 0, nullptr, P0);
    gemm(P0, wWo_v2t, bo_v2t, Bsz, D, D, 0, nullptr, P3);   // P3 = VC
    ln(visual, P1, P3, 0.5f, g_v2, be_v2, P0);              // P0 = VF

    // t_cross = attn_t2v(v_self); t_fused = LN(text + 0.5*(TS+TC))
    gemm(P1, wWv_t2v, bv_t2v, Bsz, D, D, 0, nullptr, P3);
    gemm(P3, wWo_t2v, bo_t2v, Bsz, D, D, 0, nullptr, P1);   // P1 = TC
    ln(text, P2, P1, 0.5f, g_t2, be_t2, P3);                // P3 = TF

    // v_out = VF + ffn_v(VF)
    gemm(P0, wW1_v, b1_v, Bsz, HID, D, 1, nullptr, Hbuf);
    gemm(Hbuf, wW2_v, b2_v, Bsz, D, HID, 2, P0, out0);

    // t_out = TF + ffn_t(TF)
    gemm(P3, wW1_t, b1_t, Bsz, HID, D, 1, nullptr, Hbuf);
    gemm(Hbuf, wW2_t, b2_t, Bsz, D, HID, 2, P3, out1);

    // new_context
    ctxk<<<dim3((unsigned)(BD / 1024)), dim3(256), 0, stream>>>(out0, out1, out2);
}

// Round 2
// 1375.419 us; speedup vs baseline: 1.1377x; 1.1377x over previous
//
#include <hip/hip_runtime.h>
#include <stdint.h>

// EfficientFusionLayer on MI355X (gfx950).  B=16384, DIM=1024, HID=2048.
// fp32 in/out; internals bf16 MFMA (16x16x32).
// seq-len-1 MHA folded: attn(x) = x@(Wo@Wv)^T + (Wo@bv + bo)  -- one GEMM.
// GEMM staging via global_load_lds width=16 (m97 structure, ~874 TF class).

typedef unsigned short u16;
typedef __bf16 bf16x8 __attribute__((ext_vector_type(8)));
typedef float f32x4 __attribute__((ext_vector_type(4)));

__device__ __forceinline__ u16 f2bf(float f) {
    uint32_t x = __float_as_uint(f);
    uint32_t r = (x + 0x7fffu + ((x >> 16) & 1u)) >> 16;   // round-nearest-even
    return (u16)r;
}
__device__ __forceinline__ float bf2f(u16 u) {
    return __uint_as_float(((uint32_t)u) << 16);
}

// async global->LDS, 16B per lane; deposit = wave-uniform base + lane*16
__device__ __forceinline__ void glds16(const u16* g, u16* l) {
    __builtin_amdgcn_global_load_lds(
        (__attribute__((address_space(1))) void*)g,
        (__attribute__((address_space(3))) void*)l, 16, 0, 0);
}

// ---------------------------------------------------------------------------
// fp32 -> bf16 convert (4 elems/thread, n % 1024 == 0)
__global__ __launch_bounds__(256) void cvtk(const float* __restrict__ src,
                                            u16* __restrict__ dst) {
    size_t i = ((size_t)blockIdx.x * 256 + threadIdx.x) * 4;
    float4 v = *(const float4*)&src[i];
    ushort4 o;
    o.x = f2bf(v.x); o.y = f2bf(v.y); o.z = f2bf(v.z); o.w = f2bf(v.w);
    *(ushort4*)&dst[i] = o;
}

// transposing fp32 -> bf16 convert for the 4 Wv matrices (1024x1024 each)
struct Ptr4 { const float* p[4]; };
__global__ __launch_bounds__(256) void tcvtk(Ptr4 src, u16* __restrict__ dst) {
    __shared__ float t[32][33];
    const int z = blockIdx.z;
    const float* s = src.p[z];
    const int bx = blockIdx.x * 32, by = blockIdx.y * 32;
    const int tx = threadIdx.x & 31, ty = threadIdx.x >> 5;   // 32 x 8
#pragma unroll
    for (int i = 0; i < 32; i += 8)
        t[ty + i][tx] = s[(size_t)(by + ty + i) * 1024 + bx + tx];
    __syncthreads();
    u16* d = dst + (size_t)z * (1024 * 1024);
#pragma unroll
    for (int i = 0; i < 32; i += 8)
        d[(size_t)(bx + ty + i) * 1024 + by + tx] = f2bf(t[tx][ty + i]);
}

// fused bias: bc_z[r] = dot(Wo_z[r,:], bv_z) + bo_z[r]  (fp32, exact inputs)
struct BiasArgs { const float* Wo[4]; const float* bv[4]; const float* bo[4]; };
__global__ __launch_bounds__(256) void biask(BiasArgs a, float* __restrict__ out) {
    const int z = blockIdx.y;
    const int row = blockIdx.x * 4 + (threadIdx.x >> 6);
    const int lane = threadIdx.x & 63;
    const float* w = a.Wo[z] + (size_t)row * 1024 + lane * 16;
    const float* v = a.bv[z] + lane * 16;
    float s = 0.f;
#pragma unroll
    for (int i = 0; i < 16; i += 4) {
        float4 w4 = *(const float4*)&w[i];
        float4 v4 = *(const float4*)&v[i];
        s += w4.x * v4.x + w4.y * v4.y + w4.z * v4.z + w4.w * v4.w;
    }
#pragma unroll
    for (int o = 1; o < 64; o <<= 1) s += __shfl_xor(s, o);
    if (lane == 0) out[(size_t)z * 1024 + row] = s + a.bo[z][row];
}

// new_context = 0.5*(v_out + t_out)
__global__ __launch_bounds__(256) void ctxk(const float* __restrict__ a,
                                            const float* __restrict__ b,
                                            float* __restrict__ o) {
    size_t i = ((size_t)blockIdx.x * 256 + threadIdx.x) * 4;
    float4 va = *(const float4*)&a[i];
    float4 vb = *(const float4*)&b[i];
    float4 vo;
    vo.x = 0.5f * (va.x + vb.x); vo.y = 0.5f * (va.y + vb.y);
    vo.z = 0.5f * (va.z + vb.z); vo.w = 0.5f * (va.w + vb.w);
    *(float4*)&o[i] = vo;
}

// ---------------------------------------------------------------------------
// LayerNorm over D=1024: out_bf16 = LN(x_f32 + s*(a1_bf16 [+ a2_bf16])) * g + be
__global__ __launch_bounds__(256) void ln_kernel(
    const float* __restrict__ x, const u16* __restrict__ a1,
    const u16* __restrict__ a2, float s,
    const float* __restrict__ g, const float* __restrict__ be,
    u16* __restrict__ out) {
    const int tid = threadIdx.x;
    const size_t base = (size_t)blockIdx.x * 1024;
    const int i0 = tid * 4;

    float4 xv = *(const float4*)&x[base + i0];
    ushort4 u1 = *(const ushort4*)&a1[base + i0];
    float add[4] = {bf2f(u1.x), bf2f(u1.y), bf2f(u1.z), bf2f(u1.w)};
    if (a2) {
        ushort4 u2 = *(const ushort4*)&a2[base + i0];
        add[0] += bf2f(u2.x); add[1] += bf2f(u2.y);
        add[2] += bf2f(u2.z); add[3] += bf2f(u2.w);
    }
    float v[4] = {xv.x, xv.y, xv.z, xv.w};
    float sum = 0.f, ss = 0.f;
#pragma unroll
    for (int j = 0; j < 4; ++j) {
        v[j] += s * add[j];
        sum += v[j];
        ss += v[j] * v[j];
    }
#pragma unroll
    for (int o = 1; o < 64; o <<= 1) {
        sum += __shfl_xor(sum, o);
        ss  += __shfl_xor(ss, o);
    }
    __shared__ float s1[4], s2[4];
    if ((tid & 63) == 0) { s1[tid >> 6] = sum; s2[tid >> 6] = ss; }
    __syncthreads();
    sum = s1[0] + s1[1] + s1[2] + s1[3];
    ss  = s2[0] + s2[1] + s2[2] + s2[3];
    const float mean = sum * (1.f / 1024.f);
    const float var  = ss * (1.f / 1024.f) - mean * mean;
    const float inv  = rsqrtf(var + 1e-5f);

    float4 gv = *(const float4*)&g[i0];
    float4 bv = *(const float4*)&be[i0];
    ushort4 o4;
    o4.x = f2bf((v[0] - mean) * inv * gv.x + bv.x);
    o4.y = f2bf((v[1] - mean) * inv * gv.y + bv.y);
    o4.z = f2bf((v[2] - mean) * inv * gv.z + bv.z);
    o4.w = f2bf((v[3] - mean) * inv * gv.w + bv.w);
    *(ushort4*)&out[base + i0] = o4;
}

// ---------------------------------------------------------------------------
// NT GEMM: C[M,N] = A[M,K] @ W[N,K]^T + bias, bf16 in, fp32 acc.
// 128x128 tile, BK=32, 256 thr (4 waves 2x2), 4x4 of 16x16x32 MFMA per wave.
// Staging: global_load_lds width=16. Deposit = base + lane*16 (row-major
// [row][kgrp]); per-lane GLOBAL source k-group is XOR-swizzled
// (grp = (l&3)^((l>>3)&3)) so LDS holds the swizzled layout -> fragment
// b128 reads measured conflict-free (R1: SQ_LDS_BANK_CONFLICT = 0).
// mode 0: bf16 out = acc+bias   1: bf16 out = relu(acc+bias)
// mode 2: fp32 out = acc+bias+bf2f(resid)
// blockIdx.z batches with strides sA/sW/sC (elements).
__global__ __launch_bounds__(256) void gemm_bt(
    const u16* __restrict__ A, const u16* __restrict__ W,
    const float* __restrict__ bias,
    int M, int N, int K, int mode,
    const u16* __restrict__ resid,
    u16* __restrict__ out_bf, float* __restrict__ out_f,
    size_t sA, size_t sW, size_t sC) {
    __shared__ u16 As[128 * 32];
    __shared__ u16 Bs[128 * 32];

    const int tid  = threadIdx.x;
    const int lane = tid & 63;
    const int wv   = tid >> 6;
    const int wm   = wv >> 1, wn = wv & 1;
    const int M0 = blockIdx.y * 128, N0 = blockIdx.x * 128;
    const int z  = blockIdx.z;
    A += (size_t)z * sA;
    W += (size_t)z * sW;

    const f32x4 fz = {0.f, 0.f, 0.f, 0.f};
    f32x4 acc[4][4];
#pragma unroll
    for (int i = 0; i < 4; ++i)
#pragma unroll
        for (int j = 0; j < 4; ++j) acc[i][j] = fz;

    // staging: wave w covers 16-row segments w and w+4 of both tiles.
    // lane l -> row seg*16 + (l>>2), global k-group (l&3)^((l>>3)&3).
    const int rl = lane >> 2;
    const int gg = (lane & 3) ^ ((lane >> 3) & 3);
    const u16* pA0 = A + (size_t)(M0 + wv * 16 + rl) * K + gg * 8;
    const u16* pA1 = A + (size_t)(M0 + 64 + wv * 16 + rl) * K + gg * 8;
    const u16* pW0 = W + (size_t)(N0 + wv * 16 + rl) * K + gg * 8;
    const u16* pW1 = W + (size_t)(N0 + 64 + wv * 16 + rl) * K + gg * 8;
    u16* ldsA0 = &As[wv * 512];
    u16* ldsA1 = &As[(wv + 4) * 512];
    u16* ldsB0 = &Bs[wv * 512];
    u16* ldsB1 = &Bs[(wv + 4) * 512];

    // fragment read indices
    const int lr  = lane & 15;
    const int q   = lane >> 4;
    const int gsw = ((q ^ ((lr >> 1) & 3)) << 3);

    for (int k0 = 0; k0 < K; k0 += 32) {
        __syncthreads();
        glds16(pA0, ldsA0);
        glds16(pA1, ldsA1);
        glds16(pW0, ldsB0);
        glds16(pW1, ldsB1);
        pA0 += 32; pA1 += 32; pW0 += 32; pW1 += 32;
        __syncthreads();

        bf16x8 af[4], bfr[4];
#pragma unroll
        for (int mi = 0; mi < 4; ++mi)
            af[mi] = *(const bf16x8*)&As[(wm * 64 + mi * 16 + lr) * 32 + gsw];
#pragma unroll
        for (int ni = 0; ni < 4; ++ni)
            bfr[ni] = *(const bf16x8*)&Bs[(wn * 64 + ni * 16 + lr) * 32 + gsw];
#pragma unroll
        for (int mi = 0; mi < 4; ++mi)
#pragma unroll
            for (int ni = 0; ni < 4; ++ni)
                acc[mi][ni] = __builtin_amdgcn_mfma_f32_16x16x32_bf16(
                    af[mi], bfr[ni], acc[mi][ni], 0, 0, 0);
    }

    // epilogue: C/D layout col = lane&15, row = (lane>>4)*4 + reg  [m89/m91]
    const int rbase = M0 + wm * 64 + (q << 2);
    const int cbase = N0 + wn * 64 + lr;
    out_bf += (size_t)z * sC;
    out_f  += (size_t)z * sC;
#pragma unroll
    for (int mi = 0; mi < 4; ++mi) {
#pragma unroll
        for (int ni = 0; ni < 4; ++ni) {
            const int c = cbase + ni * 16;
            const float bv = bias ? bias[c] : 0.f;
#pragma unroll
            for (int r = 0; r < 4; ++r) {
                const int rr = rbase + mi * 16 + r;
                float val = acc[mi][ni][r] + bv;
                if (mode == 0) {
                    out_bf[(size_t)rr * N + c] = f2bf(val);
                } else if (mode == 1) {
                    out_bf[(size_t)rr * N + c] = f2bf(val > 0.f ? val : 0.f);
                } else {
                    out_f[(size_t)rr * N + c] =
                        val + bf2f(resid[(size_t)rr * N + c]);
                }
            }
        }
    }
}

// ---------------------------------------------------------------------------
extern "C" void kernel_launch(void* const* d_in, const int* in_sizes, int n_in,
                              void* d_out, int out_size, void* d_ws, size_t ws_size,
                              hipStream_t stream) {
    const float* visual = (const float*)d_in[0];
    const float* text   = (const float*)d_in[1];
    const float* Wv_sv  = (const float*)d_in[2];
    const float* bv_sv  = (const float*)d_in[3];
    const float* Wo_sv  = (const float*)d_in[4];
    const float* bo_sv  = (const float*)d_in[5];
    const float* Wv_st  = (const float*)d_in[6];
    const float* bv_st  = (const float*)d_in[7];
    const float* Wo_st  = (const float*)d_in[8];
    const float* bo_st  = (const float*)d_in[9];
    const float* Wv_v2t = (const float*)d_in[10];
    const float* bv_v2t = (const float*)d_in[11];
    const float* Wo_v2t = (const float*)d_in[12];
    const float* bo_v2t = (const float*)d_in[13];
    const float* Wv_t2v = (const float*)d_in[14];
    const float* bv_t2v = (const float*)d_in[15];
    const float* Wo_t2v = (const float*)d_in[16];
    const float* bo_t2v = (const float*)d_in[17];
    const float* g_v1 = (const float*)d_in[18];
    const float* be_v1 = (const float*)d_in[19];
    const float* g_t1 = (const float*)d_in[20];
    const float* be_t1 = (const float*)d_in[21];
    const float* g_v2 = (const float*)d_in[22];
    const float* be_v2 = (const float*)d_in[23];
    const float* g_t2 = (const float*)d_in[24];
    const float* be_t2 = (const float*)d_in[25];
    const float* W1_v = (const float*)d_in[26];
    const float* b1_v = (const float*)d_in[27];
    const float* W2_v = (const float*)d_in[28];
    const float* b2_v = (const float*)d_in[29];
    const float* W1_t = (const float*)d_in[30];
    const float* b1_t = (const float*)d_in[31];
    const float* W2_t = (const float*)d_in[32];
    const float* b2_t = (const float*)d_in[33];

    const int Bsz = 16384, D = 1024, HID = 2048;
    const size_t SQ = (size_t)D * D;          // 1 Mi elems
    const size_t BD = (size_t)Bsz * D;        // 16 Mi elems

    // ws layout (u16 units of SQ):
    //  0.. 4  wWc[4]        (folded attn weights, bf16)
    //  4..12  wW1_v,wW2_v,wW1_t,wW2_t (2 SQ each)
    // 12..13  bias area: bc[4] fp32 (4*1024 floats) at the front
    // 13..29  P0 | 29..45 P1 | 45..61 P2 | 61..77 P3   (activations, 16 SQ ea)
    // temp (dead until LN-v2 writes P3): wWo[4] @ P3+0..4, wWvT[4] @ P3+4..8
    // total 77 SQ * 2B = 161.5 MB
    u16* wb = (u16*)d_ws;
    u16* wWc   = wb + 0 * SQ;
    u16* wW1_v = wb + 4 * SQ;
    u16* wW2_v = wb + 6 * SQ;
    u16* wW1_t = wb + 8 * SQ;
    u16* wW2_t = wb + 10 * SQ;
    float* bcAll = (float*)(wb + 12 * SQ);
    u16* P0 = wb + 13 * SQ;
    u16* P1 = wb + 29 * SQ;
    u16* P2 = wb + 45 * SQ;
    u16* P3 = wb + 61 * SQ;
    u16* Hbuf = P0;                       // 16384x2048 spans P0+P1
    u16* wWo  = P3;                       // temp, 4 SQ
    u16* wWvT = P3 + 4 * SQ;              // temp, 4 SQ

    float* out0 = (float*)d_out;
    float* out1 = out0 + BD;
    float* out2 = out0 + 2 * BD;

    auto cvt = [&](const float* src, u16* dst, size_t n) {
        cvtk<<<dim3((unsigned)(n / 1024)), dim3(256), 0, stream>>>(src, dst);
    };
    auto gemm = [&](const u16* A, const u16* W, const float* bias, int M, int N,
                    int K, int mode, const u16* resid, void* out, int zdim,
                    size_t sA, size_t sW, size_t sC) {
        dim3 grid((unsigned)(N / 128), (unsigned)(M / 128), (unsigned)zdim);
        gemm_bt<<<grid, dim3(256), 0, stream>>>(A, W, bias, M, N, K, mode,
                                                resid, (u16*)out, (float*)out,
                                                sA, sW, sC);
    };
    auto ln = [&](const float* x, const u16* a1, const u16* a2, float s,
                  const float* g, const float* be, u16* out) {
        ln_kernel<<<dim3(Bsz), dim3(256), 0, stream>>>(x, a1, a2, s, g, be, out);
    };

    // ---- weight prep (ws re-poisoned every call; must redo) ----
    cvt(Wo_sv, wWo + 0 * SQ, SQ);
    cvt(Wo_st, wWo + 1 * SQ, SQ);
    cvt(Wo_v2t, wWo + 2 * SQ, SQ);
    cvt(Wo_t2v, wWo + 3 * SQ, SQ);
    Ptr4 wvp = {{Wv_sv, Wv_st, Wv_v2t, Wv_t2v}};
    tcvtk<<<dim3(32, 32, 4), dim3(256), 0, stream>>>(wvp, wWvT);
    cvt(W1_v, wW1_v, 2 * SQ); cvt(W2_v, wW2_v, 2 * SQ);
    cvt(W1_t, wW1_t, 2 * SQ); cvt(W2_t, wW2_t, 2 * SQ);

    // Wc_z = Wo_z @ Wv_z  (= gemm_bt(Wo_z, WvT_z)), batched z=4
    gemm(wWo, wWvT, nullptr, D, D, D, 0, nullptr, wWc, 4, SQ, SQ, SQ);
    // bc_z = Wo_z @ bv_z + bo_z (fp32)
    BiasArgs ba = {{Wo_sv, Wo_st, Wo_v2t, Wo_t2v},
                   {bv_sv, bv_st, bv_v2t, bv_t2v},
                   {bo_sv, bo_st, bo_v2t, bo_t2v}};
    biask<<<dim3(256, 4), dim3(256), 0, stream>>>(ba, bcAll);
    const float* bc_sv  = bcAll;
    const float* bc_st  = bcAll + 1024;
    const float* bc_v2t = bcAll + 2048;
    const float* bc_t2v = bcAll + 3072;

    // ---- forward ----
    // v_self = LN(visual + visual@Wc_sv^T + bc_sv)
    cvt(visual, P0, BD);
    gemm(P0, wWc + 0 * SQ, bc_sv, Bsz, D, D, 0, nullptr, P1, 1, 0, 0, 0);
    ln(visual, P1, nullptr, 1.f, g_v1, be_v1, P1);          // P1 = VS
    // t_self
    cvt(text, P0, BD);
    gemm(P0, wWc + 1 * SQ, bc_st, Bsz, D, D, 0, nullptr, P2, 1, 0, 0, 0);
    ln(text, P2, nullptr, 1.f, g_t1, be_t1, P2);            // P2 = TS

    // v_cross = TS@Wc_v2t^T + bc; v_fused = LN(visual + 0.5*(VS+VC))
    gemm(P2, wWc + 2 * SQ, bc_v2t, Bsz, D, D, 0, nullptr, P0, 1, 0, 0, 0); // P0=VC
    ln(visual, P1, P0, 0.5f, g_v2, be_v2, P3);              // P3 = VF
    // t_cross = VS@Wc_t2v^T + bc; t_fused = LN(text + 0.5*(TS+TC))
    gemm(P1, wWc + 3 * SQ, bc_t2v, Bsz, D, D, 0, nullptr, P0, 1, 0, 0, 0); // P0=TC
    ln(text, P2, P0, 0.5f, g_t2, be_t2, P2);                // P2 = TF

    // v_out = VF + ffn_v(VF)
    gemm(P3, wW1_v, b1_v, Bsz, HID, D, 1, nullptr, Hbuf, 1, 0, 0, 0);
    gemm(Hbuf, wW2_v, b2_v, Bsz, D, HID, 2, P3, out0, 1, 0, 0, 0);
    // t_out = TF + ffn_t(TF)
    gemm(P2, wW1_t, b1_t, Bsz, HID, D, 1, nullptr, Hbuf, 1, 0, 0, 0);
    gemm(Hbuf, wW2_t, b2_t, Bsz, D, HID, 2, P2, out1, 1, 0, 0, 0);

    // new_context
    ctxk<<<dim3((unsigned)(BD / 1024)), dim3(256), 0, stream>>>(out0, out1, out2);
}